// Round 1
// baseline (564.022 us; speedup 1.0000x reference)
//
#include <hip/hip_runtime.h>

#define TQs 2048
#define TKs 2048
#define DDs 512
#define NBs 8

typedef float f32x4 __attribute__((ext_vector_type(4)));
typedef short bf16x8 __attribute__((ext_vector_type(8)));
typedef short bf16x4 __attribute__((ext_vector_type(4)));

__device__ __forceinline__ unsigned short f2bf(float x){
  unsigned u = __float_as_uint(x);
  return (unsigned short)((u + 0x7fffu + ((u>>16)&1u)) >> 16);
}
__device__ __forceinline__ float bf2f(unsigned short h){
  return __uint_as_float(((unsigned)h)<<16);
}

// K0a: split k (f32) -> kh + kl (bf16 pair), elementwise
__global__ __launch_bounds__(256) void k0_split_k(const float* __restrict__ kk,
                                                  short* __restrict__ kh, short* __restrict__ kl){
  const long n4 = (long)NBs*TKs*DDs/4;
  for(long i = (long)blockIdx.x*256 + threadIdx.x; i < n4; i += (long)gridDim.x*256){
    f32x4 x = ((const f32x4*)kk)[i];
    bf16x4 h, l;
    #pragma unroll
    for(int j=0;j<4;j++){
      unsigned short hj = f2bf(x[j]);
      h[j] = (short)hj;
      l[j] = (short)f2bf(x[j] - bf2f(hj));
    }
    ((bf16x4*)kh)[i] = h;
    ((bf16x4*)kl)[i] = l;
  }
}

// K0b: v (b,t,d) f32 -> vt (b,d,t) bf16, 64x64 LDS tile transpose
__global__ __launch_bounds__(256) void k0_transpose_v(const float* __restrict__ v, short* __restrict__ vt){
  __shared__ float tile[64][65];
  int b = blockIdx.z;
  int t0 = blockIdx.x*64, d0 = blockIdx.y*64;
  int tid = threadIdx.x;
  int r = tid>>2, cs = (tid&3)*16;
  const float* src = v + ((long)b*TKs + t0 + r)*DDs + d0 + cs;
  #pragma unroll
  for(int i=0;i<4;i++){
    f32x4 x = ((const f32x4*)src)[i];
    tile[r][cs+4*i+0]=x[0]; tile[r][cs+4*i+1]=x[1]; tile[r][cs+4*i+2]=x[2]; tile[r][cs+4*i+3]=x[3];
  }
  __syncthreads();
  int dr = tid>>2, ts = (tid&3)*16;
  bf16x8 b0, b1;
  #pragma unroll
  for(int i=0;i<8;i++){ b0[i] = (short)f2bf(tile[ts+i][dr]); b1[i] = (short)f2bf(tile[ts+8+i][dr]); }
  short* dst = vt + ((long)b*DDs + d0 + dr)*TKs + t0 + ts;
  ((bf16x8*)dst)[0] = b0;
  ((bf16x8*)dst)[1] = b1;
}

// K1: qw = q @ W, bf16 split (3-MFMA) GEMM, outputs qwh+qwl bf16 pair.
// M=16384, N=512, K=512. BM=128, BN=128, BK=64. 4 waves 2x2, wave tile 64x64.
__global__ __launch_bounds__(256,2) void k1_qw(const float* __restrict__ q, const float* __restrict__ w,
                                               short* __restrict__ qwh, short* __restrict__ qwl){
  __shared__ short qah[128][72], qal[128][72];
  __shared__ short wbh[128][72], wbl[128][72];  // transposed: [e][d]
  int q0 = blockIdx.x*128, e0 = blockIdx.y*128;
  int tid = threadIdx.x, lane = tid&63, wid = tid>>6;
  int wm = wid>>1, wn = wid&1;
  f32x4 acc[4][4];
  #pragma unroll
  for(int a=0;a<4;a++)
    #pragma unroll
    for(int bq=0;bq<4;bq++) acc[a][bq] = (f32x4){0.f,0.f,0.f,0.f};
  for(int k0=0;k0<DDs;k0+=64){
    __syncthreads();
    { // stage q tile split
      int r = tid>>1, c0 = (tid&1)*32;
      const float* s = q + ((long)(q0+r))*DDs + k0 + c0;
      #pragma unroll
      for(int i=0;i<8;i++){
        f32x4 x = ((const f32x4*)s)[i];
        bf16x4 h,l;
        #pragma unroll
        for(int j=0;j<4;j++){ unsigned short hj=f2bf(x[j]); h[j]=(short)hj; l[j]=(short)f2bf(x[j]-bf2f(hj)); }
        *(bf16x4*)&qah[r][c0+4*i] = h;
        *(bf16x4*)&qal[r][c0+4*i] = l;
      }
    }
    { // stage W tile transposed + split
      int d = tid>>2, es = (tid&3)*32;
      const float* s = w + ((long)(k0+d))*DDs + e0 + es;
      #pragma unroll
      for(int i=0;i<8;i++){
        f32x4 x = ((const f32x4*)s)[i];
        #pragma unroll
        for(int j=0;j<4;j++){
          unsigned short hj=f2bf(x[j]);
          wbh[es+4*i+j][d] = (short)hj;
          wbl[es+4*i+j][d] = (short)f2bf(x[j]-bf2f(hj));
        }
      }
    }
    __syncthreads();
    #pragma unroll
    for(int ks=0;ks<2;ks++){
      int kof = ks*32 + (lane>>4)*8;
      bf16x8 ah[4], al[4], bh[4], bl[4];
      #pragma unroll
      for(int mf=0;mf<4;mf++){
        ah[mf] = *(bf16x8*)&qah[wm*64+mf*16+(lane&15)][kof];
        al[mf] = *(bf16x8*)&qal[wm*64+mf*16+(lane&15)][kof];
      }
      #pragma unroll
      for(int nf=0;nf<4;nf++){
        bh[nf] = *(bf16x8*)&wbh[wn*64+nf*16+(lane&15)][kof];
        bl[nf] = *(bf16x8*)&wbl[wn*64+nf*16+(lane&15)][kof];
      }
      #pragma unroll
      for(int mf=0;mf<4;mf++)
      #pragma unroll
      for(int nf=0;nf<4;nf++){
        acc[mf][nf] = __builtin_amdgcn_mfma_f32_16x16x32_bf16(ah[mf], bh[nf], acc[mf][nf],0,0,0);
        acc[mf][nf] = __builtin_amdgcn_mfma_f32_16x16x32_bf16(ah[mf], bl[nf], acc[mf][nf],0,0,0);
        acc[mf][nf] = __builtin_amdgcn_mfma_f32_16x16x32_bf16(al[mf], bh[nf], acc[mf][nf],0,0,0);
      }
    }
  }
  int rr = (lane>>4)*4, cc = lane&15;
  #pragma unroll
  for(int mf=0;mf<4;mf++)
  #pragma unroll
  for(int nf=0;nf<4;nf++)
  #pragma unroll
  for(int r2=0;r2<4;r2++){
    long row = q0 + wm*64 + mf*16 + rr + r2;
    long col = e0 + wn*64 + nf*16 + cc;
    float s = acc[mf][nf][r2];
    unsigned short h = f2bf(s);
    qwh[row*DDs + col] = (short)h;
    qwl[row*DDs + col] = (short)f2bf(s - bf2f(h));
  }
}

// K2a: scores (bf16-split 3-MFMA), mask, online (m,l), write raw S into attn region.
// WG = 4 waves x 16 rows = 64 rows; t-chunk = 512 (grid.y=4); qw frags resident in regs.
__global__ __launch_bounds__(256,2) void k2a(const short* __restrict__ qwh, const short* __restrict__ qwl,
                                             const short* __restrict__ kh, const short* __restrict__ kl,
                                             const int* __restrict__ mask, float* __restrict__ attn,
                                             float* __restrict__ m_ws, float* __restrict__ l_ws){
  __shared__ short kht[32][520], klt[32][520];  // pad 8 -> row stride 1040B (2-way banks)
  int rb = blockIdx.x;             // 0..255
  int chunk = blockIdx.y;          // 0..3
  int tid = threadIdx.x, lane = tid&63, wid = tid>>6;
  int b = rb>>5;
  long qrow0 = (long)rb*64 + wid*16;   // global row (includes b*2048)
  bf16x8 ah[16], al[16];
  {
    const short* ph = qwh + (qrow0 + (lane&15))*DDs + (lane>>4)*8;
    const short* pl = qwl + (qrow0 + (lane&15))*DDs + (lane>>4)*8;
    #pragma unroll
    for(int kc=0;kc<16;kc++){
      ah[kc] = *(const bf16x8*)(ph + kc*32);
      al[kc] = *(const bf16x8*)(pl + kc*32);
    }
  }
  float m_st[4], l_st[4];
  #pragma unroll
  for(int r=0;r<4;r++){ m_st[r]=-1e30f; l_st[r]=0.f; }
  const short* khb = kh + (long)b*TKs*DDs;
  const short* klb = kl + (long)b*TKs*DDs;
  for(int it=0; it<16; ++it){
    long t0 = (long)chunk*512 + it*32;
    int mv[2][4];
    #pragma unroll
    for(int nf=0;nf<2;nf++)
    #pragma unroll
    for(int r=0;r<4;r++)
      mv[nf][r] = mask[(qrow0 + (lane>>4)*4 + r)*TKs + t0 + nf*16 + (lane&15)];
    __syncthreads();
    { // stage k tile pair: 32 t-rows x 512 d
      int r = tid>>3, seg = tid&7;
      const short* sh = khb + (t0 + r)*DDs + seg*64;
      const short* sl = klb + (t0 + r)*DDs + seg*64;
      #pragma unroll
      for(int i=0;i<8;i++){
        *(bf16x8*)&kht[r][seg*64 + i*8] = *(const bf16x8*)(sh + i*8);
        *(bf16x8*)&klt[r][seg*64 + i*8] = *(const bf16x8*)(sl + i*8);
      }
    }
    __syncthreads();
    f32x4 acc[2][3];
    #pragma unroll
    for(int nf=0;nf<2;nf++)
      #pragma unroll
      for(int c=0;c<3;c++) acc[nf][c]=(f32x4){0.f,0.f,0.f,0.f};
    #pragma unroll
    for(int ks=0;ks<16;ks++){
      int kof = ks*32 + (lane>>4)*8;
      #pragma unroll
      for(int nf=0;nf<2;nf++){
        bf16x8 bh = *(bf16x8*)&kht[nf*16+(lane&15)][kof];
        bf16x8 bl = *(bf16x8*)&klt[nf*16+(lane&15)][kof];
        acc[nf][0] = __builtin_amdgcn_mfma_f32_16x16x32_bf16(ah[ks], bh, acc[nf][0],0,0,0);
        acc[nf][1] = __builtin_amdgcn_mfma_f32_16x16x32_bf16(ah[ks], bl, acc[nf][1],0,0,0);
        acc[nf][2] = __builtin_amdgcn_mfma_f32_16x16x32_bf16(al[ks], bh, acc[nf][2],0,0,0);
      }
    }
    #pragma unroll
    for(int r=0;r<4;r++){
      float s0 = acc[0][0][r] + acc[0][1][r] + acc[0][2][r];
      float s1 = acc[1][0][r] + acc[1][1][r] + acc[1][2][r];
      if(mv[0][r]) s0 = -3e38f;
      if(mv[1][r]) s1 = -3e38f;
      float mx = fmaxf(s0,s1);
      #pragma unroll
      for(int d=1; d<16; d<<=1) mx = fmaxf(mx, __shfl_xor(mx, d, 16));
      float mold = m_st[r];
      float mnew = fmaxf(mold, mx);
      float p = __expf(s0-mnew) + __expf(s1-mnew);
      #pragma unroll
      for(int d=1; d<16; d<<=1) p += __shfl_xor(p, d, 16);
      l_st[r] = l_st[r]*__expf(mold-mnew) + p;
      m_st[r] = mnew;
      long row = qrow0 + (lane>>4)*4 + r;
      attn[row*TKs + t0 + (lane&15)] = s0;
      attn[row*TKs + t0 + 16 + (lane&15)] = s1;
    }
  }
  if((lane&15)==0){
    #pragma unroll
    for(int r=0;r<4;r++){
      long row = qrow0 + (lane>>4)*4 + r;
      m_ws[row*4 + chunk] = m_st[r];
      l_ws[row*4 + chunk] = l_st[r];
    }
  }
}

// K2b: merge stats, normalize S -> attention (in place), PV via bf16 MFMA.
// WG = 32 rows, 4 waves each owning a 128-wide dv slice. t-step 32.
__global__ __launch_bounds__(256,2) void k2b(const short* __restrict__ vt, const float* __restrict__ m_ws,
                                             const float* __restrict__ l_ws, float* __restrict__ attn,
                                             float* __restrict__ outp){
  __shared__ short at[32][40];
  __shared__ short vtile[512][40];
  __shared__ float ms[32], rls[32];
  int rb = blockIdx.x;   // 0..511
  long row0 = (long)rb*32;
  int b = rb>>6;
  int tid=threadIdx.x, lane=tid&63, wid=tid>>6;
  if(tid < 32){
    long row = row0 + tid;
    float m0=m_ws[row*4+0], m1=m_ws[row*4+1], m2=m_ws[row*4+2], m3=m_ws[row*4+3];
    float M = fmaxf(fmaxf(m0,m1),fmaxf(m2,m3));
    float L = l_ws[row*4+0]*__expf(m0-M) + l_ws[row*4+1]*__expf(m1-M)
            + l_ws[row*4+2]*__expf(m2-M) + l_ws[row*4+3]*__expf(m3-M);
    ms[tid] = M;
    rls[tid] = 1.0f/L;
  }
  f32x4 acc[2][8];
  #pragma unroll
  for(int mf=0;mf<2;mf++)
    #pragma unroll
    for(int nf=0;nf<8;nf++) acc[mf][nf]=(f32x4){0.f,0.f,0.f,0.f};
  const short* vb = vt + (long)b*DDs*TKs;
  float* arow = attn + row0*TKs;
  __syncthreads();
  for(int it=0; it<64; ++it){
    long t0 = (long)it*32;
    { // phase A: S -> a (write back), a -> bf16 LDS
      int r = tid>>3, c0 = (tid&7)*4;
      float* p = arow + (long)r*TKs + t0 + c0;
      f32x4 s = *(const f32x4*)p;
      float M = ms[r], RL = rls[r];
      f32x4 a;
      #pragma unroll
      for(int j=0;j<4;j++) a[j] = __expf(s[j]-M)*RL;
      *(f32x4*)p = a;
      bf16x4 ab;
      #pragma unroll
      for(int j=0;j<4;j++) ab[j] = (short)f2bf(a[j]);
      *(bf16x4*)&at[r][c0] = ab;
    }
    { // stage v tile: 512 dv x 32 t
      #pragma unroll
      for(int rr=0;rr<2;rr++){
        int dv = tid*2+rr;
        const short* s = vb + (long)dv*TKs + t0;
        #pragma unroll
        for(int i=0;i<4;i++)
          *(bf16x8*)&vtile[dv][i*8] = *(const bf16x8*)(s + i*8);
      }
    }
    __syncthreads();
    bf16x8 af[2], bfr[8];
    #pragma unroll
    for(int mf=0;mf<2;mf++) af[mf] = *(bf16x8*)&at[mf*16+(lane&15)][(lane>>4)*8];
    #pragma unroll
    for(int nf=0;nf<8;nf++) bfr[nf] = *(bf16x8*)&vtile[wid*128+nf*16+(lane&15)][(lane>>4)*8];
    #pragma unroll
    for(int mf=0;mf<2;mf++)
    #pragma unroll
    for(int nf=0;nf<8;nf++)
      acc[mf][nf] = __builtin_amdgcn_mfma_f32_16x16x32_bf16(af[mf], bfr[nf], acc[mf][nf],0,0,0);
    __syncthreads();
  }
  #pragma unroll
  for(int mf=0;mf<2;mf++)
  #pragma unroll
  for(int nf=0;nf<8;nf++)
  #pragma unroll
  for(int r=0;r<4;r++){
    long row = row0 + mf*16 + (lane>>4)*4 + r;
    long col = wid*128 + nf*16 + (lane&15);
    outp[row*DDs + col] = acc[mf][nf][r];
  }
}

extern "C" void kernel_launch(void* const* d_in, const int* in_sizes, int n_in,
                              void* d_out, int out_size, void* d_ws, size_t ws_size,
                              hipStream_t stream) {
  const float* q    = (const float*)d_in[0];
  const float* k    = (const float*)d_in[1];
  const float* v    = (const float*)d_in[2];
  const int*   mask = (const int*)d_in[3];
  const float* w    = (const float*)d_in[4];
  float* outp = (float*)d_out;
  float* attn = (float*)d_out + (long)NBs*TQs*DDs;
  char* ws = (char*)d_ws;
  const long NE = (long)NBs*TKs*DDs;      // 8,388,608 elements
  short* kh  = (short*)ws;                 // 2*NE bytes each
  short* kl  = (short*)(ws + 2*NE);
  short* vt  = (short*)(ws + 4*NE);
  short* qwh = (short*)(ws + 6*NE);
  short* qwl = (short*)(ws + 8*NE);
  float* m_ws = (float*)(ws + 10*NE);              // 16384*4 f32
  float* l_ws = (float*)(ws + 10*NE + 65536*4);
  hipLaunchKernelGGL(k0_split_k,     dim3(1024),    dim3(256), 0, stream, k, kh, kl);
  hipLaunchKernelGGL(k0_transpose_v, dim3(32,8,8),  dim3(256), 0, stream, v, vt);
  hipLaunchKernelGGL(k1_qw,          dim3(128,4),   dim3(256), 0, stream, q, w, qwh, qwl);
  hipLaunchKernelGGL(k2a,            dim3(256,4),   dim3(256), 0, stream, qwh, qwl, kh, kl, mask, attn, m_ws, l_ws);
  hipLaunchKernelGGL(k2b,            dim3(512),     dim3(256), 0, stream, vt, m_ws, l_ws, attn, outp);
}

// Round 2
// 399.763 us; speedup vs baseline: 1.4109x; 1.4109x over previous
//
#include <hip/hip_runtime.h>
#include <stdint.h>

#define TQs 2048
#define TKs 2048
#define DDs 512
#define NBs 8

typedef float f32x4 __attribute__((ext_vector_type(4)));
typedef short bf16x8 __attribute__((ext_vector_type(8)));
typedef short bf16x4 __attribute__((ext_vector_type(4)));

__device__ __forceinline__ unsigned short f2bf(float x){
  unsigned u = __float_as_uint(x);
  return (unsigned short)((u + 0x7fffu + ((u>>16)&1u)) >> 16);
}
__device__ __forceinline__ float bf2f(unsigned short h){
  return __uint_as_float(((unsigned)h)<<16);
}

// global -> LDS direct DMA, 16B per lane; LDS dest = uniform base + lane*16.
__device__ __forceinline__ void gload16(const void* g, void* l){
  __builtin_amdgcn_global_load_lds(
      (const __attribute__((address_space(1))) unsigned int*)(unsigned long long)(uintptr_t)g,
      (__attribute__((address_space(3))) unsigned int*)(unsigned int)(uintptr_t)l,
      16, 0, 0);
}

// K0a: split k (f32) -> kh + kl (bf16 pair), row-major [b][t][d]
__global__ __launch_bounds__(256) void k0_split_k(const float* __restrict__ kk,
                                                  short* __restrict__ kh, short* __restrict__ kl){
  const long n4 = (long)NBs*TKs*DDs/4;
  for(long i = (long)blockIdx.x*256 + threadIdx.x; i < n4; i += (long)gridDim.x*256){
    f32x4 x = ((const f32x4*)kk)[i];
    bf16x4 h, l;
    #pragma unroll
    for(int j=0;j<4;j++){
      unsigned short hj = f2bf(x[j]);
      h[j] = (short)hj;
      l[j] = (short)f2bf(x[j] - bf2f(hj));
    }
    ((bf16x4*)kh)[i] = h;
    ((bf16x4*)kl)[i] = l;
  }
}

// K0b: v (b,t,d) f32 -> vt (b,d,t) bf16
__global__ __launch_bounds__(256) void k0_transpose_v(const float* __restrict__ v, short* __restrict__ vt){
  __shared__ float tile[64][65];
  int b = blockIdx.z;
  int t0 = blockIdx.x*64, d0 = blockIdx.y*64;
  int tid = threadIdx.x;
  int r = tid>>2, cs = (tid&3)*16;
  const float* src = v + ((long)b*TKs + t0 + r)*DDs + d0 + cs;
  #pragma unroll
  for(int i=0;i<4;i++){
    f32x4 x = ((const f32x4*)src)[i];
    tile[r][cs+4*i+0]=x[0]; tile[r][cs+4*i+1]=x[1]; tile[r][cs+4*i+2]=x[2]; tile[r][cs+4*i+3]=x[3];
  }
  __syncthreads();
  int dr = tid>>2, ts = (tid&3)*16;
  bf16x8 b0, b1;
  #pragma unroll
  for(int i=0;i<8;i++){ b0[i] = (short)f2bf(tile[ts+i][dr]); b1[i] = (short)f2bf(tile[ts+8+i][dr]); }
  short* dst = vt + ((long)b*DDs + d0 + dr)*TKs + t0 + ts;
  ((bf16x8*)dst)[0] = b0;
  ((bf16x8*)dst)[1] = b1;
}

// K0c: w (d,e) f32 -> wth/wtl (e,d) bf16 split
__global__ __launch_bounds__(256) void k0_wt(const float* __restrict__ wsrc,
                                             short* __restrict__ wth, short* __restrict__ wtl){
  __shared__ float tile[64][65];
  int d0 = blockIdx.x*64, e0 = blockIdx.y*64;
  int tid = threadIdx.x;
  int r = tid>>2, cs = (tid&3)*16;
  const float* src = wsrc + ((long)(d0 + r))*DDs + e0 + cs;
  #pragma unroll
  for(int i=0;i<4;i++){
    f32x4 x = ((const f32x4*)src)[i];
    tile[r][cs+4*i+0]=x[0]; tile[r][cs+4*i+1]=x[1]; tile[r][cs+4*i+2]=x[2]; tile[r][cs+4*i+3]=x[3];
  }
  __syncthreads();
  int er = tid>>2, ds = (tid&3)*16;
  bf16x8 h0,h1,l0,l1;
  #pragma unroll
  for(int i=0;i<8;i++){
    float x = tile[ds+i][er];
    unsigned short hh = f2bf(x);
    h0[i] = (short)hh; l0[i] = (short)f2bf(x - bf2f(hh));
  }
  #pragma unroll
  for(int i=0;i<8;i++){
    float x = tile[ds+8+i][er];
    unsigned short hh = f2bf(x);
    h1[i] = (short)hh; l1[i] = (short)f2bf(x - bf2f(hh));
  }
  short* dh = wth + ((long)(e0+er))*DDs + d0 + ds;
  short* dl = wtl + ((long)(e0+er))*DDs + d0 + ds;
  ((bf16x8*)dh)[0] = h0; ((bf16x8*)dh)[1] = h1;
  ((bf16x8*)dl)[0] = l0; ((bf16x8*)dl)[1] = l1;
}

// K1: qw = q @ W (bf16 3-term split). A reg-staged+split to fragment-linear LDS,
// B (pre-split/transposed wt) via global_load_lds. BM=128,BN=128,BK=64, 4 waves 2x2.
__global__ __launch_bounds__(256,2) void k1_qw(const float* __restrict__ q,
                                               const short* __restrict__ wth, const short* __restrict__ wtl,
                                               short* __restrict__ qwh, short* __restrict__ qwl){
  __shared__ short qah[8192], qal[8192];   // 1024 cells x 8 shorts
  __shared__ short wbh[8192], wbl[8192];
  int q0 = blockIdx.x*128, e0 = blockIdx.y*128;
  int tid = threadIdx.x, lane = tid&63, w4 = tid>>6;
  int wm = w4>>1, wn = w4&1;
  int i15 = lane&15, g4 = lane>>4;
  f32x4 acc[4][4];
  #pragma unroll
  for(int a=0;a<4;a++)
    #pragma unroll
    for(int bq=0;bq<4;bq++) acc[a][bq] = (f32x4){0.f,0.f,0.f,0.f};
  for(int k0=0;k0<DDs;k0+=64){
    __syncthreads();
    // B stage via DMA: 16 instrs (J=0..15), cell block J*64
    #pragma unroll
    for(int j=0;j<4;j++){
      int J = j*4 + w4;
      long so = (long)(e0 + (J>>1)*16 + i15)*DDs + k0 + ((J&1)*4 + g4)*8;
      gload16(wth + so, &wbh[J*512]);
      gload16(wtl + so, &wbl[J*512]);
    }
    // A stage: read f32, split, linear ds_write
    #pragma unroll
    for(int j=0;j<4;j++){
      int c = j*256 + tid;
      int ci = c&15, cg = (c>>4)&3, cks = (c>>6)&1, crb = c>>7;
      const float* s = q + (long)(q0 + crb*16 + ci)*DDs + k0 + (cks*4+cg)*8;
      f32x4 x0 = ((const f32x4*)s)[0];
      f32x4 x1 = ((const f32x4*)s)[1];
      bf16x8 h, l;
      #pragma unroll
      for(int jj=0;jj<4;jj++){
        unsigned short hj = f2bf(x0[jj]);
        h[jj] = (short)hj; l[jj] = (short)f2bf(x0[jj]-bf2f(hj));
      }
      #pragma unroll
      for(int jj=0;jj<4;jj++){
        unsigned short hj = f2bf(x1[jj]);
        h[4+jj] = (short)hj; l[4+jj] = (short)f2bf(x1[jj]-bf2f(hj));
      }
      *(bf16x8*)&qah[c*8] = h;
      *(bf16x8*)&qal[c*8] = l;
    }
    __syncthreads();
    #pragma unroll
    for(int ks=0;ks<2;ks++){
      bf16x8 a_h[4], a_l[4], b_h[4], b_l[4];
      #pragma unroll
      for(int mf=0;mf<4;mf++){
        int c = ((wm*4+mf)*2+ks)*64 + lane;
        a_h[mf] = *(const bf16x8*)&qah[c*8];
        a_l[mf] = *(const bf16x8*)&qal[c*8];
      }
      #pragma unroll
      for(int nf=0;nf<4;nf++){
        int c = ((wn*4+nf)*2+ks)*64 + lane;
        b_h[nf] = *(const bf16x8*)&wbh[c*8];
        b_l[nf] = *(const bf16x8*)&wbl[c*8];
      }
      #pragma unroll
      for(int mf=0;mf<4;mf++)
      #pragma unroll
      for(int nf=0;nf<4;nf++){
        acc[mf][nf] = __builtin_amdgcn_mfma_f32_16x16x32_bf16(a_h[mf], b_h[nf], acc[mf][nf],0,0,0);
        acc[mf][nf] = __builtin_amdgcn_mfma_f32_16x16x32_bf16(a_h[mf], b_l[nf], acc[mf][nf],0,0,0);
        acc[mf][nf] = __builtin_amdgcn_mfma_f32_16x16x32_bf16(a_l[mf], b_h[nf], acc[mf][nf],0,0,0);
      }
    }
  }
  int rr = g4*4, cc = i15;
  #pragma unroll
  for(int mf=0;mf<4;mf++)
  #pragma unroll
  for(int nf=0;nf<4;nf++)
  #pragma unroll
  for(int r2=0;r2<4;r2++){
    long row = q0 + wm*64 + mf*16 + rr + r2;
    long col = e0 + wn*64 + nf*16 + cc;
    float s = acc[mf][nf][r2];
    unsigned short h = f2bf(s);
    qwh[row*DDs + col] = (short)h;
    qwl[row*DDs + col] = (short)f2bf(s - bf2f(h));
  }
}

// K2a: scores (bf16 3-term), mask, online (m,l), raw S -> attn region.
// K-tile in fragment-linear LDS via global_load_lds. 64 rows x 512-t chunk.
__global__ __launch_bounds__(256,2) void k2a(const short* __restrict__ qwh, const short* __restrict__ qwl,
                                             const short* __restrict__ kh, const short* __restrict__ kl,
                                             const int* __restrict__ mask, float* __restrict__ attn,
                                             float* __restrict__ m_ws, float* __restrict__ l_ws){
  __shared__ short kfh[16384];   // 2048 cells x 16B = 32KB
  __shared__ short kfl[16384];
  int rb = blockIdx.x;             // 0..255
  int chunk = blockIdx.y;          // 0..3
  int tid = threadIdx.x, lane = tid&63, w = tid>>6;
  int b = rb>>5;
  long qrow0 = (long)rb*64 + w*16;
  int i15 = lane&15, g4 = lane>>4;
  bf16x8 ah[16], al[16];
  {
    const short* ph = qwh + (qrow0 + i15)*DDs + g4*8;
    const short* pl = qwl + (qrow0 + i15)*DDs + g4*8;
    #pragma unroll
    for(int kc=0;kc<16;kc++){
      ah[kc] = *(const bf16x8*)(ph + kc*32);
      al[kc] = *(const bf16x8*)(pl + kc*32);
    }
  }
  float m_st[4], l_st[4];
  #pragma unroll
  for(int r=0;r<4;r++){ m_st[r]=-1e30f; l_st[r]=0.f; }
  const short* khb = kh + (long)b*TKs*DDs;
  const short* klb = kl + (long)b*TKs*DDs;
  for(int it=0; it<16; ++it){
    int t0 = chunk*512 + it*32;
    __syncthreads();                       // prev-iter frag reads done
    #pragma unroll
    for(int j=0;j<8;j++){
      int J = j*4 + w;                     // 0..31: nf=J>>4, ks=J&15
      long so = (long)(t0 + ((J>>4)<<4) + i15)*DDs + ((J&15)*4 + g4)*8;
      gload16(khb + so, &kfh[J*512]);
      gload16(klb + so, &kfl[J*512]);
    }
    int mv[2][4];
    #pragma unroll
    for(int nf=0;nf<2;nf++)
      #pragma unroll
      for(int r=0;r<4;r++)
        mv[nf][r] = mask[(qrow0 + g4*4 + r)*TKs + t0 + nf*16 + i15];
    __syncthreads();                       // DMA complete
    f32x4 acc[2][3];
    #pragma unroll
    for(int nf=0;nf<2;nf++)
      #pragma unroll
      for(int c=0;c<3;c++) acc[nf][c]=(f32x4){0.f,0.f,0.f,0.f};
    #pragma unroll
    for(int ks=0;ks<16;ks++){
      #pragma unroll
      for(int nf=0;nf<2;nf++){
        bf16x8 bh = *(const bf16x8*)&kfh[((nf*16+ks)*64 + lane)*8];
        bf16x8 bl = *(const bf16x8*)&kfl[((nf*16+ks)*64 + lane)*8];
        acc[nf][0] = __builtin_amdgcn_mfma_f32_16x16x32_bf16(ah[ks], bh, acc[nf][0],0,0,0);
        acc[nf][1] = __builtin_amdgcn_mfma_f32_16x16x32_bf16(ah[ks], bl, acc[nf][1],0,0,0);
        acc[nf][2] = __builtin_amdgcn_mfma_f32_16x16x32_bf16(al[ks], bh, acc[nf][2],0,0,0);
      }
    }
    #pragma unroll
    for(int r=0;r<4;r++){
      float s0 = acc[0][0][r] + acc[0][1][r] + acc[0][2][r];
      float s1 = acc[1][0][r] + acc[1][1][r] + acc[1][2][r];
      if(mv[0][r]) s0 = -3e38f;
      if(mv[1][r]) s1 = -3e38f;
      float mx = fmaxf(s0,s1);
      #pragma unroll
      for(int d=1; d<16; d<<=1) mx = fmaxf(mx, __shfl_xor(mx, d, 16));
      float mold = m_st[r];
      float mnew = fmaxf(mold, mx);
      float p = __expf(s0-mnew) + __expf(s1-mnew);
      #pragma unroll
      for(int d=1; d<16; d<<=1) p += __shfl_xor(p, d, 16);
      l_st[r] = l_st[r]*__expf(mold-mnew) + p;
      m_st[r] = mnew;
      long row = qrow0 + g4*4 + r;
      attn[row*TKs + t0 + i15] = s0;
      attn[row*TKs + t0 + 16 + i15] = s1;
    }
  }
  if(i15==0){
    #pragma unroll
    for(int r=0;r<4;r++){
      long row = qrow0 + g4*4 + r;
      m_ws[row*4 + chunk] = m_st[r];
      l_ws[row*4 + chunk] = l_st[r];
    }
  }
}

// K2b: merge stats, normalize S -> attention (in place), PV via bf16 MFMA.
// 64 rows/block, 4 waves each own 128-wide dv slice; v-tile fragment-linear via DMA.
__global__ __launch_bounds__(256,2) void k2b(const short* __restrict__ vt, const float* __restrict__ m_ws,
                                             const float* __restrict__ l_ws, float* __restrict__ attn,
                                             float* __restrict__ outp){
  __shared__ short vf[16384];     // 2048 cells (512 dv x 4 t8)
  __shared__ short at[2048];      // 256 cells (64 r x 4 t8)
  __shared__ float ms[64], rls[64];
  int rb = blockIdx.x;            // 0..255
  long row0 = (long)rb*64;
  int b = rb>>5;
  int tid=threadIdx.x, lane=tid&63, w=tid>>6;
  int i15 = lane&15, g4 = lane>>4;
  if(tid < 64){
    long row = row0 + tid;
    float m0=m_ws[row*4+0], m1=m_ws[row*4+1], m2=m_ws[row*4+2], m3=m_ws[row*4+3];
    float M = fmaxf(fmaxf(m0,m1),fmaxf(m2,m3));
    float L = l_ws[row*4+0]*__expf(m0-M) + l_ws[row*4+1]*__expf(m1-M)
            + l_ws[row*4+2]*__expf(m2-M) + l_ws[row*4+3]*__expf(m3-M);
    ms[tid] = M;
    rls[tid] = 1.0f/L;
  }
  f32x4 acc[4][8];
  #pragma unroll
  for(int mf=0;mf<4;mf++)
    #pragma unroll
    for(int nf=0;nf<8;nf++) acc[mf][nf]=(f32x4){0.f,0.f,0.f,0.f};
  const short* vb = vt + (long)b*DDs*TKs;
  float* arow = attn + row0*TKs;
  int r_ = tid>>2, t8w = tid&3;
  __syncthreads();
  for(int it=0; it<64; ++it){
    int t0 = it*32;
    // issue v-tile DMA first (overlaps with normalize's HBM reads)
    #pragma unroll
    for(int j=0;j<8;j++){
      int J = j*4 + w;                 // dv block 0..31
      long so = (long)(J*16 + i15)*TKs + t0 + g4*8;
      gload16(vb + so, &vf[J*512]);
    }
    { // normalize S -> attention, and bf16 copy into fragment-linear at[]
      float* p = arow + (long)r_*TKs + t0 + t8w*8;
      f32x4 s0v = ((const f32x4*)p)[0];
      f32x4 s1v = ((const f32x4*)p)[1];
      float M = ms[r_], RL = rls[r_];
      f32x4 a0, a1;
      #pragma unroll
      for(int j=0;j<4;j++){ a0[j] = __expf(s0v[j]-M)*RL; a1[j] = __expf(s1v[j]-M)*RL; }
      ((f32x4*)p)[0] = a0;
      ((f32x4*)p)[1] = a1;
      bf16x8 ab;
      #pragma unroll
      for(int j=0;j<4;j++){ ab[j] = (short)f2bf(a0[j]); ab[4+j] = (short)f2bf(a1[j]); }
      int cell = ((r_>>4)<<6) + (t8w<<4) + (r_&15);
      *(bf16x8*)&at[cell*8] = ab;
    }
    __syncthreads();
    bf16x8 af[4], bfr[8];
    #pragma unroll
    for(int mf=0;mf<4;mf++) af[mf] = *(const bf16x8*)&at[(mf*64 + lane)*8];
    #pragma unroll
    for(int nf=0;nf<8;nf++) bfr[nf] = *(const bf16x8*)&vf[((w*8+nf)*64 + lane)*8];
    #pragma unroll
    for(int mf=0;mf<4;mf++)
    #pragma unroll
    for(int nf=0;nf<8;nf++)
      acc[mf][nf] = __builtin_amdgcn_mfma_f32_16x16x32_bf16(af[mf], bfr[nf], acc[mf][nf],0,0,0);
    __syncthreads();
  }
  #pragma unroll
  for(int mf=0;mf<4;mf++)
  #pragma unroll
  for(int nf=0;nf<8;nf++)
  #pragma unroll
  for(int r2=0;r2<4;r2++){
    long row = row0 + mf*16 + g4*4 + r2;
    long col = w*128 + nf*16 + i15;
    outp[row*DDs + col] = acc[mf][nf][r2];
  }
}

extern "C" void kernel_launch(void* const* d_in, const int* in_sizes, int n_in,
                              void* d_out, int out_size, void* d_ws, size_t ws_size,
                              hipStream_t stream) {
  const float* q    = (const float*)d_in[0];
  const float* k    = (const float*)d_in[1];
  const float* v    = (const float*)d_in[2];
  const int*   mask = (const int*)d_in[3];
  const float* wsrc = (const float*)d_in[4];
  float* outp = (float*)d_out;
  float* attn = (float*)d_out + (long)NBs*TQs*DDs;
  char* ws = (char*)d_ws;
  const long NE = (long)NBs*TKs*DDs;      // 8,388,608 elements
  short* kh  = (short*)ws;
  short* kl  = (short*)(ws + 2*NE);
  short* vt  = (short*)(ws + 4*NE);
  short* qwh = (short*)(ws + 6*NE);
  short* qwl = (short*)(ws + 8*NE);
  float* m_ws = (float*)(ws + 10*NE);
  float* l_ws = (float*)(ws + 10*NE + 65536*4);
  // wt split lives at the head of the attn region (dead before k2a overwrites it)
  short* wth = (short*)attn;
  short* wtl = (short*)attn + 262144;
  hipLaunchKernelGGL(k0_split_k,     dim3(1024),    dim3(256), 0, stream, k, kh, kl);
  hipLaunchKernelGGL(k0_transpose_v, dim3(32,8,8),  dim3(256), 0, stream, v, vt);
  hipLaunchKernelGGL(k0_wt,          dim3(8,8),     dim3(256), 0, stream, wsrc, wth, wtl);
  hipLaunchKernelGGL(k1_qw,          dim3(128,4),   dim3(256), 0, stream, q, wth, wtl, qwh, qwl);
  hipLaunchKernelGGL(k2a,            dim3(256,4),   dim3(256), 0, stream, qwh, qwl, kh, kl, mask, attn, m_ws, l_ws);
  hipLaunchKernelGGL(k2b,            dim3(256),     dim3(256), 0, stream, vt, m_ws, l_ws, attn, outp);
}

// Round 3
// 321.130 us; speedup vs baseline: 1.7564x; 1.2449x over previous
//
#include <hip/hip_runtime.h>
#include <stdint.h>

#define TQs 2048
#define TKs 2048
#define DDs 512
#define NBs 8

typedef float f32x4 __attribute__((ext_vector_type(4)));
typedef short bf16x8 __attribute__((ext_vector_type(8)));
typedef short bf16x4 __attribute__((ext_vector_type(4)));
typedef _Float16 half8 __attribute__((ext_vector_type(8)));

__device__ __forceinline__ unsigned short f2bf(float x){
  unsigned u = __float_as_uint(x);
  return (unsigned short)((u + 0x7fffu + ((u>>16)&1u)) >> 16);
}
__device__ __forceinline__ float bf2f(unsigned short h){
  return __uint_as_float(((unsigned)h)<<16);
}

// global -> LDS direct DMA, 16B per lane; LDS dest = uniform base + lane*16.
__device__ __forceinline__ void gload16(const void* g, void* l){
  __builtin_amdgcn_global_load_lds(
      (const __attribute__((address_space(1))) unsigned int*)(unsigned long long)(uintptr_t)g,
      (__attribute__((address_space(3))) unsigned int*)(unsigned int)(uintptr_t)l,
      16, 0, 0);
}

// K0a: k (f32) -> kf (f16)
__global__ __launch_bounds__(256) void k0_kf(const float* __restrict__ kk, _Float16* __restrict__ kf){
  const long n8 = (long)NBs*TKs*DDs/8;
  for(long i = (long)blockIdx.x*256 + threadIdx.x; i < n8; i += (long)gridDim.x*256){
    f32x4 x0 = ((const f32x4*)kk)[2*i];
    f32x4 x1 = ((const f32x4*)kk)[2*i+1];
    half8 h;
    #pragma unroll
    for(int j=0;j<4;j++){ h[j] = (_Float16)x0[j]; h[4+j] = (_Float16)x1[j]; }
    ((half8*)kf)[i] = h;
  }
}

// K0b: v (b,t,d) f32 -> vt (b,d,t) bf16
__global__ __launch_bounds__(256) void k0_transpose_v(const float* __restrict__ v, short* __restrict__ vt){
  __shared__ float tile[64][65];
  int b = blockIdx.z;
  int t0 = blockIdx.x*64, d0 = blockIdx.y*64;
  int tid = threadIdx.x;
  int r = tid>>2, cs = (tid&3)*16;
  const float* src = v + ((long)b*TKs + t0 + r)*DDs + d0 + cs;
  #pragma unroll
  for(int i=0;i<4;i++){
    f32x4 x = ((const f32x4*)src)[i];
    tile[r][cs+4*i+0]=x[0]; tile[r][cs+4*i+1]=x[1]; tile[r][cs+4*i+2]=x[2]; tile[r][cs+4*i+3]=x[3];
  }
  __syncthreads();
  int dr = tid>>2, ts = (tid&3)*16;
  bf16x8 b0, b1;
  #pragma unroll
  for(int i=0;i<8;i++){ b0[i] = (short)f2bf(tile[ts+i][dr]); b1[i] = (short)f2bf(tile[ts+8+i][dr]); }
  short* dst = vt + ((long)b*DDs + d0 + dr)*TKs + t0 + ts;
  ((bf16x8*)dst)[0] = b0;
  ((bf16x8*)dst)[1] = b1;
}

// K0c: w (d,e) f32 -> wth/wtl (e,d) bf16 split (for k1's 3-term bf16 GEMM)
__global__ __launch_bounds__(256) void k0_wt(const float* __restrict__ wsrc,
                                             short* __restrict__ wth, short* __restrict__ wtl){
  __shared__ float tile[64][65];
  int d0 = blockIdx.x*64, e0 = blockIdx.y*64;
  int tid = threadIdx.x;
  int r = tid>>2, cs = (tid&3)*16;
  const float* src = wsrc + ((long)(d0 + r))*DDs + e0 + cs;
  #pragma unroll
  for(int i=0;i<4;i++){
    f32x4 x = ((const f32x4*)src)[i];
    tile[r][cs+4*i+0]=x[0]; tile[r][cs+4*i+1]=x[1]; tile[r][cs+4*i+2]=x[2]; tile[r][cs+4*i+3]=x[3];
  }
  __syncthreads();
  int er = tid>>2, ds = (tid&3)*16;
  bf16x8 h0,h1,l0,l1;
  #pragma unroll
  for(int i=0;i<8;i++){
    float x = tile[ds+i][er];
    unsigned short hh = f2bf(x);
    h0[i] = (short)hh; l0[i] = (short)f2bf(x - bf2f(hh));
  }
  #pragma unroll
  for(int i=0;i<8;i++){
    float x = tile[ds+8+i][er];
    unsigned short hh = f2bf(x);
    h1[i] = (short)hh; l1[i] = (short)f2bf(x - bf2f(hh));
  }
  short* dh = wth + ((long)(e0+er))*DDs + d0 + ds;
  short* dl = wtl + ((long)(e0+er))*DDs + d0 + ds;
  ((bf16x8*)dh)[0] = h0; ((bf16x8*)dh)[1] = h1;
  ((bf16x8*)dl)[0] = l0; ((bf16x8*)dl)[1] = l1;
}

// K1: qw = q @ W (bf16 3-term). Output: f16 hi/lo split (qwh16 + qwl16).
__global__ __launch_bounds__(256,2) void k1_qw(const float* __restrict__ q,
                                               const short* __restrict__ wth, const short* __restrict__ wtl,
                                               _Float16* __restrict__ qwh, _Float16* __restrict__ qwl){
  __shared__ short qah[8192], qal[8192];
  __shared__ short wbh[8192], wbl[8192];
  int q0 = blockIdx.x*128, e0 = blockIdx.y*128;
  int tid = threadIdx.x, lane = tid&63, w4 = tid>>6;
  int wm = w4>>1, wn = w4&1;
  int i15 = lane&15, g4 = lane>>4;
  f32x4 acc[4][4];
  #pragma unroll
  for(int a=0;a<4;a++)
    #pragma unroll
    for(int bq=0;bq<4;bq++) acc[a][bq] = (f32x4){0.f,0.f,0.f,0.f};
  for(int k0=0;k0<DDs;k0+=64){
    __syncthreads();
    #pragma unroll
    for(int j=0;j<4;j++){
      int J = j*4 + w4;
      long so = (long)(e0 + (J>>1)*16 + i15)*DDs + k0 + ((J&1)*4 + g4)*8;
      gload16(wth + so, &wbh[J*512]);
      gload16(wtl + so, &wbl[J*512]);
    }
    #pragma unroll
    for(int j=0;j<4;j++){
      int c = j*256 + tid;
      int ci = c&15, cg = (c>>4)&3, cks = (c>>6)&1, crb = c>>7;
      const float* s = q + (long)(q0 + crb*16 + ci)*DDs + k0 + (cks*4+cg)*8;
      f32x4 x0 = ((const f32x4*)s)[0];
      f32x4 x1 = ((const f32x4*)s)[1];
      bf16x8 h, l;
      #pragma unroll
      for(int jj=0;jj<4;jj++){
        unsigned short hj = f2bf(x0[jj]);
        h[jj] = (short)hj; l[jj] = (short)f2bf(x0[jj]-bf2f(hj));
      }
      #pragma unroll
      for(int jj=0;jj<4;jj++){
        unsigned short hj = f2bf(x1[jj]);
        h[4+jj] = (short)hj; l[4+jj] = (short)f2bf(x1[jj]-bf2f(hj));
      }
      *(bf16x8*)&qah[c*8] = h;
      *(bf16x8*)&qal[c*8] = l;
    }
    __syncthreads();
    #pragma unroll
    for(int ks=0;ks<2;ks++){
      bf16x8 a_h[4], a_l[4], b_h[4], b_l[4];
      #pragma unroll
      for(int mf=0;mf<4;mf++){
        int c = ((wm*4+mf)*2+ks)*64 + lane;
        a_h[mf] = *(const bf16x8*)&qah[c*8];
        a_l[mf] = *(const bf16x8*)&qal[c*8];
      }
      #pragma unroll
      for(int nf=0;nf<4;nf++){
        int c = ((wn*4+nf)*2+ks)*64 + lane;
        b_h[nf] = *(const bf16x8*)&wbh[c*8];
        b_l[nf] = *(const bf16x8*)&wbl[c*8];
      }
      #pragma unroll
      for(int mf=0;mf<4;mf++)
      #pragma unroll
      for(int nf=0;nf<4;nf++){
        acc[mf][nf] = __builtin_amdgcn_mfma_f32_16x16x32_bf16(a_h[mf], b_h[nf], acc[mf][nf],0,0,0);
        acc[mf][nf] = __builtin_amdgcn_mfma_f32_16x16x32_bf16(a_h[mf], b_l[nf], acc[mf][nf],0,0,0);
        acc[mf][nf] = __builtin_amdgcn_mfma_f32_16x16x32_bf16(a_l[mf], b_h[nf], acc[mf][nf],0,0,0);
      }
    }
  }
  int rr = g4*4, cc = i15;
  #pragma unroll
  for(int mf=0;mf<4;mf++)
  #pragma unroll
  for(int nf=0;nf<4;nf++)
  #pragma unroll
  for(int r2=0;r2<4;r2++){
    long row = q0 + wm*64 + mf*16 + rr + r2;
    long col = e0 + wn*64 + nf*16 + cc;
    float s = acc[mf][nf][r2];
    _Float16 h = (_Float16)s;
    qwh[row*DDs + col] = h;
    qwl[row*DDs + col] = (_Float16)(s - (float)h);
  }
}

// K2a: scores = qw @ k^T, f16 2-term (A split, B single), double-buffered K DMA,
// per-lane online (m,l) with end-of-chunk merge, raw masked S -> attn region.
__global__ __launch_bounds__(256,2) void k2a(const _Float16* __restrict__ qwh, const _Float16* __restrict__ qwl,
                                             const _Float16* __restrict__ kf,
                                             const int* __restrict__ mask, float* __restrict__ attn,
                                             float* __restrict__ m_ws, float* __restrict__ l_ws){
  __shared__ _Float16 kb[2][16384];   // 2 x 32KB
  int rb = blockIdx.x;                // 0..255
  int chunk = blockIdx.y;             // 0..3
  int tid = threadIdx.x, lane = tid&63, w = tid>>6;
  int b = rb>>5;
  long qrow0 = (long)rb*64 + w*16;
  int i15 = lane&15, g4 = lane>>4;
  half8 ah[16], al[16];
  {
    const _Float16* ph = qwh + (qrow0 + i15)*DDs + g4*8;
    const _Float16* pl = qwl + (qrow0 + i15)*DDs + g4*8;
    #pragma unroll
    for(int kc=0;kc<16;kc++){
      ah[kc] = *(const half8*)(ph + kc*32);
      al[kc] = *(const half8*)(pl + kc*32);
    }
  }
  float m_st[4], l_st[4];
  #pragma unroll
  for(int r=0;r<4;r++){ m_st[r]=-1e30f; l_st[r]=0.f; }
  const _Float16* kbase = kf + (long)b*TKs*DDs;
  // prologue: stage tile 0
  {
    int t0 = chunk*512;
    #pragma unroll
    for(int j=0;j<8;j++){
      int J = j*4 + w;
      long so = (long)(t0 + ((J>>4)<<4) + i15)*DDs + (J&15)*32 + g4*8;
      gload16(kbase + so, &kb[0][J*512]);
    }
  }
  __syncthreads();
  int cur = 0;
  for(int it=0; it<16; ++it){
    int t0 = chunk*512 + it*32;
    if(it < 15){
      int t1 = t0 + 32;
      #pragma unroll
      for(int j=0;j<8;j++){
        int J = j*4 + w;
        long so = (long)(t1 + ((J>>4)<<4) + i15)*DDs + (J&15)*32 + g4*8;
        gload16(kbase + so, &kb[cur^1][J*512]);
      }
    }
    int mv[2][4];
    #pragma unroll
    for(int nf=0;nf<2;nf++)
      #pragma unroll
      for(int r=0;r<4;r++)
        mv[nf][r] = mask[(qrow0 + g4*4 + r)*TKs + t0 + nf*16 + i15];
    f32x4 acc[2];
    acc[0]=(f32x4){0.f,0.f,0.f,0.f}; acc[1]=(f32x4){0.f,0.f,0.f,0.f};
    #pragma unroll
    for(int ks=0;ks<16;ks++){
      #pragma unroll
      for(int nf=0;nf<2;nf++){
        half8 bh = *(const half8*)&kb[cur][((nf*16+ks)*64 + lane)*8];
        acc[nf] = __builtin_amdgcn_mfma_f32_16x16x32_f16(ah[ks], bh, acc[nf],0,0,0);
        acc[nf] = __builtin_amdgcn_mfma_f32_16x16x32_f16(al[ks], bh, acc[nf],0,0,0);
      }
    }
    #pragma unroll
    for(int r=0;r<4;r++){
      float s0 = acc[0][r];
      float s1 = acc[1][r];
      if(mv[0][r]) s0 = -3e38f;
      if(mv[1][r]) s1 = -3e38f;
      float mo = m_st[r];
      float mn = fmaxf(mo, fmaxf(s0,s1));
      l_st[r] = l_st[r]*__expf(mo-mn) + __expf(s0-mn) + __expf(s1-mn);
      m_st[r] = mn;
      long row = qrow0 + g4*4 + r;
      attn[row*TKs + t0 + i15] = s0;
      attn[row*TKs + t0 + 16 + i15] = s1;
    }
    __syncthreads();
    cur ^= 1;
  }
  // one-time 16-lane merge of (m,l)
  #pragma unroll
  for(int r=0;r<4;r++){
    #pragma unroll
    for(int d=1; d<16; d<<=1){
      float m2 = __shfl_xor(m_st[r], d, 16);
      float l2 = __shfl_xor(l_st[r], d, 16);
      float mn = fmaxf(m_st[r], m2);
      l_st[r] = l_st[r]*__expf(m_st[r]-mn) + l2*__expf(m2-mn);
      m_st[r] = mn;
    }
  }
  if(i15==0){
    #pragma unroll
    for(int r=0;r<4;r++){
      long row = qrow0 + g4*4 + r;
      m_ws[row*4 + chunk] = m_st[r];
      l_ws[row*4 + chunk] = l_st[r];
    }
  }
}

// K2b: merge stats, normalize S -> attention (in place), PV via bf16 MFMA.
// Double-buffered V DMA + at[2]; software-pipelined normalize; 1 barrier/iter.
__global__ __launch_bounds__(256,2) void k2b(const short* __restrict__ vt, const float* __restrict__ m_ws,
                                             const float* __restrict__ l_ws, float* __restrict__ attn,
                                             float* __restrict__ outp){
  __shared__ short vf[2][16384];   // 2 x 32KB
  __shared__ short at2[2][2048];   // 2 x 4KB
  __shared__ float ms[64], rls[64];
  int rb = blockIdx.x;             // 0..255
  long row0 = (long)rb*64;
  int b = rb>>5;
  int tid=threadIdx.x, lane=tid&63, w=tid>>6;
  int i15 = lane&15, g4 = lane>>4;
  const short* vb = vt + (long)b*DDs*TKs;
  float* arow = attn + row0*TKs;
  int r_ = tid>>2, t8w = tid&3;
  // prologue: DMA v tile 0; stats
  #pragma unroll
  for(int j=0;j<8;j++){
    int J = j*4 + w;
    long so = (long)(J*16 + i15)*TKs + g4*8;
    gload16(vb + so, &vf[0][J*512]);
  }
  if(tid < 64){
    long row = row0 + tid;
    float m0=m_ws[row*4+0], m1=m_ws[row*4+1], m2=m_ws[row*4+2], m3=m_ws[row*4+3];
    float M = fmaxf(fmaxf(m0,m1),fmaxf(m2,m3));
    float L = l_ws[row*4+0]*__expf(m0-M) + l_ws[row*4+1]*__expf(m1-M)
            + l_ws[row*4+2]*__expf(m2-M) + l_ws[row*4+3]*__expf(m3-M);
    ms[tid] = M;
    rls[tid] = 1.0f/L;
  }
  __syncthreads();
  // normalize tile 0 -> at2[0]
  {
    float* p = arow + (long)r_*TKs + t8w*8;
    f32x4 s0v = ((const f32x4*)p)[0];
    f32x4 s1v = ((const f32x4*)p)[1];
    float M = ms[r_], RL = rls[r_];
    f32x4 a0, a1;
    #pragma unroll
    for(int j=0;j<4;j++){ a0[j] = __expf(s0v[j]-M)*RL; a1[j] = __expf(s1v[j]-M)*RL; }
    ((f32x4*)p)[0] = a0;
    ((f32x4*)p)[1] = a1;
    bf16x8 ab;
    #pragma unroll
    for(int j=0;j<4;j++){ ab[j] = (short)f2bf(a0[j]); ab[4+j] = (short)f2bf(a1[j]); }
    int cell = ((r_>>4)<<6) + (t8w<<4) + (r_&15);
    *(bf16x8*)&at2[0][cell*8] = ab;
  }
  __syncthreads();
  f32x4 acc[4][8];
  #pragma unroll
  for(int mf=0;mf<4;mf++)
    #pragma unroll
    for(int nf=0;nf<8;nf++) acc[mf][nf]=(f32x4){0.f,0.f,0.f,0.f};
  int c = 0;
  for(int it=0; it<64; ++it){
    f32x4 s0v, s1v;
    if(it < 63){
      int t1 = (it+1)*32;
      #pragma unroll
      for(int j=0;j<8;j++){
        int J = j*4 + w;
        long so = (long)(J*16 + i15)*TKs + t1 + g4*8;
        gload16(vb + so, &vf[c^1][J*512]);
      }
      float* p = arow + (long)r_*TKs + t1 + t8w*8;
      s0v = ((const f32x4*)p)[0];
      s1v = ((const f32x4*)p)[1];
    }
    // MFMA on current tile
    bf16x8 af[4], bfr[8];
    #pragma unroll
    for(int mf=0;mf<4;mf++) af[mf] = *(const bf16x8*)&at2[c][(mf*64 + lane)*8];
    #pragma unroll
    for(int nf=0;nf<8;nf++) bfr[nf] = *(const bf16x8*)&vf[c][((w*8+nf)*64 + lane)*8];
    #pragma unroll
    for(int mf=0;mf<4;mf++)
    #pragma unroll
    for(int nf=0;nf<8;nf++)
      acc[mf][nf] = __builtin_amdgcn_mfma_f32_16x16x32_bf16(af[mf], bfr[nf], acc[mf][nf],0,0,0);
    // normalize next tile into at2[c^1]
    if(it < 63){
      int t1 = (it+1)*32;
      float* p = arow + (long)r_*TKs + t1 + t8w*8;
      float M = ms[r_], RL = rls[r_];
      f32x4 a0, a1;
      #pragma unroll
      for(int j=0;j<4;j++){ a0[j] = __expf(s0v[j]-M)*RL; a1[j] = __expf(s1v[j]-M)*RL; }
      ((f32x4*)p)[0] = a0;
      ((f32x4*)p)[1] = a1;
      bf16x8 ab;
      #pragma unroll
      for(int j=0;j<4;j++){ ab[j] = (short)f2bf(a0[j]); ab[4+j] = (short)f2bf(a1[j]); }
      int cell = ((r_>>4)<<6) + (t8w<<4) + (r_&15);
      *(bf16x8*)&at2[c^1][cell*8] = ab;
    }
    __syncthreads();
    c ^= 1;
  }
  #pragma unroll
  for(int mf=0;mf<4;mf++)
  #pragma unroll
  for(int nf=0;nf<8;nf++)
  #pragma unroll
  for(int r2=0;r2<4;r2++){
    long row = row0 + mf*16 + g4*4 + r2;
    long col = w*128 + nf*16 + i15;
    outp[row*DDs + col] = acc[mf][nf][r2];
  }
}

extern "C" void kernel_launch(void* const* d_in, const int* in_sizes, int n_in,
                              void* d_out, int out_size, void* d_ws, size_t ws_size,
                              hipStream_t stream) {
  const float* q    = (const float*)d_in[0];
  const float* k    = (const float*)d_in[1];
  const float* v    = (const float*)d_in[2];
  const int*   mask = (const int*)d_in[3];
  const float* wsrc = (const float*)d_in[4];
  float* outp = (float*)d_out;
  float* attn = (float*)d_out + (long)NBs*TQs*DDs;
  char* ws = (char*)d_ws;
  const long NE = (long)NBs*TKs*DDs;      // 8,388,608 elements
  _Float16* kf  = (_Float16*)ws;                 // 2NE bytes
  short*    vt  = (short*)(ws + 2*NE);           // 2NE bytes
  _Float16* qwh = (_Float16*)(ws + 4*NE);        // 2NE bytes
  _Float16* qwl = (_Float16*)(ws + 6*NE);        // 2NE bytes
  float* m_ws = (float*)(ws + 8*NE);             // 65536 f32
  float* l_ws = (float*)(ws + 8*NE + 65536*4);
  // wt split lives at the head of the attn region (dead before k2a overwrites it)
  short* wth = (short*)attn;
  short* wtl = (short*)attn + 262144;
  hipLaunchKernelGGL(k0_kf,          dim3(1024),    dim3(256), 0, stream, k, kf);
  hipLaunchKernelGGL(k0_transpose_v, dim3(32,8,8),  dim3(256), 0, stream, v, vt);
  hipLaunchKernelGGL(k0_wt,          dim3(8,8),     dim3(256), 0, stream, wsrc, wth, wtl);
  hipLaunchKernelGGL(k1_qw,          dim3(128,4),   dim3(256), 0, stream, q, wth, wtl, qwh, qwl);
  hipLaunchKernelGGL(k2a,            dim3(256,4),   dim3(256), 0, stream, qwh, qwl, kf, mask, attn, m_ws, l_ws);
  hipLaunchKernelGGL(k2b,            dim3(256),     dim3(256), 0, stream, vt, m_ws, l_ws, attn, outp);
}